// Round 3
// baseline (214.715 us; speedup 1.0000x reference)
//
#include <hip/hip_runtime.h>
#include <cfloat>

#define NB 4
#define NN 4096
#define NC 256

typedef _Float16 f16;
typedef _Float16 f16x8 __attribute__((ext_vector_type(8)));
typedef float f32x16 __attribute__((ext_vector_type(16)));

__device__ __forceinline__ void gl_lds16(const void* g, void* l) {
    __builtin_amdgcn_global_load_lds(
        (const __attribute__((address_space(1))) unsigned int*)g,
        (__attribute__((address_space(3))) unsigned int*)l, 16, 0, 0);
}

// ---- prep: fp32 -> f16 hi/lo, interleaved at 16B granularity + diag ----
// xhl[row][gp*16 + 0..7] = hi granule gp (8 f16), [gp*16 + 8..15] = lo granule gp.
// Row pitch 512 f16 = 1024 B. One 64 B read covers a K=16 chunk (hi+lo).
__global__ __launch_bounds__(256) void prep_kernel(const float* __restrict__ x,
                                                   f16* __restrict__ xhl,
                                                   float* __restrict__ diag) {
    const int lane = threadIdx.x & 63;
    const int wave = threadIdx.x >> 6;
    const int row  = (blockIdx.x << 2) + wave;            // 0..16383
    const float4 v = ((const float4*)(x + (size_t)row * NC))[lane];
    union { f16 h[4]; uint2 u; } H, L;
    float vv[4] = {v.x, v.y, v.z, v.w};
    float s = 0.f;
    #pragma unroll
    for (int k = 0; k < 4; ++k) {
        H.h[k] = (f16)vv[k];
        L.h[k] = (f16)(vv[k] - (float)H.h[k]);
        s = fmaf(vv[k], vv[k], s);
    }
    f16* base = xhl + (size_t)row * 512 + (lane >> 1) * 16 + (lane & 1) * 4;
    *(uint2*)base       = H.u;   // hi half-granule
    *(uint2*)(base + 8) = L.u;   // lo half-granule
    #pragma unroll
    for (int off = 32; off; off >>= 1) s += __shfl_xor(s, off, 64);
    if (lane == 0) diag[row] = s;
}

// ---------------- main MFMA kernel ----------------
#define TI 64
#define TJ 512
#define KCB 16
#define NCH (NC / KCB)   // 16
#define NJT (NN / TJ)    // 8

__global__ __launch_bounds__(512, 2) void fcm_mfma(const f16* __restrict__ xhl,
                                                   const float* __restrict__ diag,
                                                   float* __restrict__ out) {
    __shared__ f16 As[TI * 512];        // 64 KB  persistent A (hi/lo interleaved, swizzled)
    __shared__ f16 Bs[2][TJ * 32];      // 64 KB  double-buffered B chunks
    __shared__ float Scr[TI * 4 * 3];   //  3 KB  cross-wave merge

    const int tid   = threadIdx.x;
    const int bx    = blockIdx.x;
    const int batch = (bx & 7) >> 1;                  // batch -> XCD pair
    const int band  = ((bx >> 3) << 1) | (bx & 1);    // 0..63
    const int i0    = band * TI;

    const f16* __restrict__ xb   = xhl + (size_t)batch * NN * 512;
    const float* __restrict__ db = diag + (size_t)batch * NN;

    const int w    = tid >> 6;
    const int lane = tid & 63;
    const int wy   = w >> 2;       // row half (0..1)
    const int wx   = w & 3;        // col quarter (0..3), 128 cols each
    const int l31  = lane & 31;
    const int gh   = lane >> 5;    // K-granule half

    // ---- A stage once: row-swizzled (slot = gp ^ (row&7)), 1 instr per row ----
    #pragma unroll
    for (int it = 0; it < 8; ++it) {
        const int row  = w * 8 + it;
        const int gsrc = (lane >> 1) ^ (row & 7);
        gl_lds16(xb + (size_t)(i0 + row) * 512 + gsrc * 16 + (lane & 1) * 8,
                 As + row * 512);
    }

    // B staging lane constants: per instr 16 cols x 64 B; slot swizzle key (c>>1)&3
    const int scl = lane >> 2;          // col within 16-col group
    const int sp  = lane & 3;           // stored slot

    // stage B chunk 0 of j-tile 0 into buf 0
    #pragma unroll
    for (int it = 0; it < 4; ++it) {
        const int c0 = (w * 4 + it) * 16;
        const int c  = c0 + scl;
        const int ps = sp ^ ((c >> 1) & 3);
        gl_lds16(xb + (size_t)c * 512 + ps * 8, &Bs[0][c0 * 32]);
    }

    // A-fragment row + swizzle base
    const int R   = wy * 32 + l31;
    const int Rsw = R & 7;

    // per-lane running top-2 (+argmin) for 16 row-slots (32x32 C layout rows)
    float m1[16], m2[16]; int i1[16];
    #pragma unroll
    for (int r = 0; r < 16; ++r) { m1[r] = FLT_MAX; m2[r] = FLT_MAX; i1[r] = 0x7fffffff; }

    for (int jt = 0; jt < NJT; ++jt) {
        const int j0 = jt * TJ;
        f32x16 acc[4];
        #pragma unroll
        for (int ct = 0; ct < 4; ++ct)
            #pragma unroll
            for (int p = 0; p < 16; ++p) acc[ct][p] = 0.f;

        #pragma unroll 2
        for (int kc = 0; kc < NCH; ++kc) {
            __syncthreads();   // drains vmcnt -> buf[kc&1] staged (loads flew a full chunk)
            // issue staging for the NEXT chunk into the other buffer
            if (kc + 1 < NCH) {
                #pragma unroll
                for (int it = 0; it < 4; ++it) {
                    const int c0 = (w * 4 + it) * 16;
                    const int c  = c0 + scl;
                    const int ps = sp ^ ((c >> 1) & 3);
                    gl_lds16(xb + (size_t)(j0 + c) * 512 + (kc + 1) * 32 + ps * 8,
                             &Bs[(kc + 1) & 1][c0 * 32]);
                }
            } else if (jt + 1 < NJT) {
                const int j0n = j0 + TJ;
                #pragma unroll
                for (int it = 0; it < 4; ++it) {
                    const int c0 = (w * 4 + it) * 16;
                    const int c  = c0 + scl;
                    const int ps = sp ^ ((c >> 1) & 3);
                    gl_lds16(xb + (size_t)(j0n + c) * 512 + ps * 8,
                             &Bs[0][c0 * 32]);
                }
            }
            // compute on buf[kc&1]
            const int sA = ((kc << 1) | gh) ^ Rsw;
            const f16x8 afh = *(const f16x8*)&As[R * 512 + sA * 16];
            const f16x8 afl = *(const f16x8*)&As[R * 512 + sA * 16 + 8];
            const f16* bb = Bs[kc & 1];
            f16x8 bfh[4], bfl[4];
            #pragma unroll
            for (int ct = 0; ct < 4; ++ct) {
                const int c   = wx * 128 + ct * 32 + l31;
                const int swz = (c >> 1) & 3;
                bfh[ct] = *(const f16x8*)&bb[c * 32 + (((gh << 1) | 0) ^ swz) * 8];
                bfl[ct] = *(const f16x8*)&bb[c * 32 + (((gh << 1) | 1) ^ swz) * 8];
            }
            #pragma unroll
            for (int ct = 0; ct < 4; ++ct) {
                acc[ct] = __builtin_amdgcn_mfma_f32_32x32x16_f16(afh, bfh[ct], acc[ct], 0, 0, 0);
                acc[ct] = __builtin_amdgcn_mfma_f32_32x32x16_f16(afh, bfl[ct], acc[ct], 0, 0, 0);
                acc[ct] = __builtin_amdgcn_mfma_f32_32x32x16_f16(afl, bfh[ct], acc[ct], 0, 0, 0);
            }
        }

        // fold j-tile into running top-2; key = diag_j - 2*dot (monotone in dist)
        #pragma unroll
        for (int ct = 0; ct < 4; ++ct) {
            const int c  = wx * 128 + ct * 32 + l31;
            const int j  = j0 + c;
            const float dj = db[j];             // hot in L1/L2 (16 KB per batch)
            #pragma unroll
            for (int reg = 0; reg < 16; ++reg) {
                const int rloc = (reg & 3) + ((reg >> 2) << 3) + (gh << 2);
                const int rg   = i0 + wy * 32 + rloc;
                float v = fmaf(-2.0f, acc[ct][reg], dj);
                v = (j == rg) ? FLT_MAX : v;    // mask self
                const bool lt = v < m1[reg];    // strict: ascending j keeps earliest
                m2[reg] = fminf(m2[reg], fmaxf(m1[reg], v));
                m1[reg] = fminf(m1[reg], v);
                i1[reg] = lt ? j : i1[reg];
            }
        }
    }

    // butterfly merge across the 32 col-lanes (same row set within each half)
    #pragma unroll
    for (int reg = 0; reg < 16; ++reg) {
        float a1 = m1[reg], a2 = m2[reg]; int ai = i1[reg];
        #pragma unroll
        for (int msk = 1; msk < 32; msk <<= 1) {
            const float o1 = __shfl_xor(a1, msk, 64);
            const float o2 = __shfl_xor(a2, msk, 64);
            const int   oi = __shfl_xor(ai, msk, 64);
            const bool take = (o1 < a1) || (o1 == a1 && oi < ai);
            const float keep = take ? a1 : o1;
            a2 = fminf(fminf(a2, o2), keep);
            a1 = take ? o1 : a1;
            ai = take ? oi : ai;
        }
        m1[reg] = a1; m2[reg] = a2; i1[reg] = ai;
    }
    if (l31 == 0) {
        #pragma unroll
        for (int reg = 0; reg < 16; ++reg) {
            const int rloc = (reg & 3) + ((reg >> 2) << 3) + (gh << 2);
            float* p = &Scr[((wy * 32 + rloc) * 4 + wx) * 3];
            p[0] = m1[reg]; p[1] = __int_as_float(i1[reg]); p[2] = m2[reg];
        }
    }
    __syncthreads();
    if (tid < TI) {
        float M1 = FLT_MAX, M2 = FLT_MAX; int I1 = 0x7fffffff;
        #pragma unroll
        for (int t = 0; t < 4; ++t) {
            const float* p = &Scr[(tid * 4 + t) * 3];
            const float o1 = p[0]; const int oi = __float_as_int(p[1]); const float o2 = p[2];
            const bool take = (o1 < M1) || (o1 == M1 && oi < I1);
            const float keep = take ? M1 : o1;
            M2 = fminf(fminf(M2, o2), keep);
            M1 = take ? o1 : M1;
            I1 = take ? oi : I1;
        }
        const int   gi = i0 + tid;
        const float di = db[gi];
        const float d1 = sqrtf(fmaxf(di + M1, 0.0f) + 1e-9f);
        const float d2 = sqrtf(fmaxf(di + M2, 0.0f) + 1e-9f);
        const float e  = expf(d1);
        const float pred = (d1 / d2 < 0.6f) ? 2.0f / (1.0f + e)
                                            : 2.0f / (1.0f + 2.0f * e);
        out[(size_t)batch * NN + gi] = pred;
        out[(size_t)NB * NN + (size_t)batch * NN + gi] = (float)I1;
    }
}

// ---------------- fp32 fallback (round-1, known-correct) if ws too small ----------------
__global__ __launch_bounds__(256) void diag_kernel(const float* __restrict__ x,
                                                   float* __restrict__ diag) {
    const int lane = threadIdx.x & 63;
    const int wave = threadIdx.x >> 6;
    const int row  = (blockIdx.x << 2) + wave;
    const float4 v = ((const float4*)(x + (size_t)row * NC))[lane];
    float s = v.x * v.x + v.y * v.y + v.z * v.z + v.w * v.w;
    #pragma unroll
    for (int off = 32; off; off >>= 1) s += __shfl_xor(s, off, 64);
    if (lane == 0) diag[row] = s;
}

#define FTI 64
#define FTJ 256
#define FKC 16

__global__ __launch_bounds__(256) void fcm_fallback(const float* __restrict__ x,
                                                    const float* __restrict__ diag,
                                                    float* __restrict__ out) {
    __shared__ float Asf[FKC * FTI];
    __shared__ float Bsf[FKC * FTJ];
    __shared__ float Dsf[FTJ];
    __shared__ float Scrf[FTI * 32 * 3];

    const int tid = threadIdx.x;
    const int bx  = blockIdx.x;
    const int batch = (bx & 7) >> 1;
    const int tile  = ((bx >> 3) << 1) | (bx & 1);
    const int i0    = tile * FTI;
    const float* __restrict__ xb = x + (size_t)batch * NN * NC;
    const float* __restrict__ db = diag + (size_t)batch * NN;
    const int tx = tid & 31;
    const int ty = tid >> 5;
    const int sr  = tid & 63;
    const int sk0 = (tid >> 6) << 2;

    float m1[8], m2[8]; int i1[8];
    #pragma unroll
    for (int r = 0; r < 8; ++r) { m1[r] = FLT_MAX; m2[r] = FLT_MAX; i1[r] = 0; }

    for (int jt = 0; jt < NN / FTJ; ++jt) {
        const int j0 = jt * FTJ;
        __syncthreads();
        Dsf[tid] = db[j0 + tid];
        float acc[8][8];
        #pragma unroll
        for (int r = 0; r < 8; ++r)
            #pragma unroll
            for (int c = 0; c < 8; ++c) acc[r][c] = 0.0f;
        float4 pa  = *(const float4*)(xb + (size_t)(i0 + sr) * NC + sk0);
        const float* bsrc = xb + (size_t)(j0 + tid) * NC;
        float4 pb0 = *(const float4*)(bsrc + 0);
        float4 pb1 = *(const float4*)(bsrc + 4);
        float4 pb2 = *(const float4*)(bsrc + 8);
        float4 pb3 = *(const float4*)(bsrc + 12);
        for (int kc = 0; kc < NC / FKC; ++kc) {
            __syncthreads();
            Asf[(sk0 + 0) * FTI + sr] = pa.x;
            Asf[(sk0 + 1) * FTI + sr] = pa.y;
            Asf[(sk0 + 2) * FTI + sr] = pa.z;
            Asf[(sk0 + 3) * FTI + sr] = pa.w;
            Bsf[ 0 * FTJ + tid] = pb0.x; Bsf[ 1 * FTJ + tid] = pb0.y;
            Bsf[ 2 * FTJ + tid] = pb0.z; Bsf[ 3 * FTJ + tid] = pb0.w;
            Bsf[ 4 * FTJ + tid] = pb1.x; Bsf[ 5 * FTJ + tid] = pb1.y;
            Bsf[ 6 * FTJ + tid] = pb1.z; Bsf[ 7 * FTJ + tid] = pb1.w;
            Bsf[ 8 * FTJ + tid] = pb2.x; Bsf[ 9 * FTJ + tid] = pb2.y;
            Bsf[10 * FTJ + tid] = pb2.z; Bsf[11 * FTJ + tid] = pb2.w;
            Bsf[12 * FTJ + tid] = pb3.x; Bsf[13 * FTJ + tid] = pb3.y;
            Bsf[14 * FTJ + tid] = pb3.z; Bsf[15 * FTJ + tid] = pb3.w;
            if (kc + 1 < NC / FKC) {
                const int kb = (kc + 1) * FKC;
                pa  = *(const float4*)(xb + (size_t)(i0 + sr) * NC + kb + sk0);
                pb0 = *(const float4*)(bsrc + kb + 0);
                pb1 = *(const float4*)(bsrc + kb + 4);
                pb2 = *(const float4*)(bsrc + kb + 8);
                pb3 = *(const float4*)(bsrc + kb + 12);
            }
            __syncthreads();
            #pragma unroll
            for (int k = 0; k < FKC; ++k) {
                float av[8], bv[8];
                *(float4*)&av[0] = *(const float4*)&Asf[k * FTI + ty * 8];
                *(float4*)&av[4] = *(const float4*)&Asf[k * FTI + ty * 8 + 4];
                *(float4*)&bv[0] = *(const float4*)&Bsf[k * FTJ + tx * 8];
                *(float4*)&bv[4] = *(const float4*)&Bsf[k * FTJ + tx * 8 + 4];
                #pragma unroll
                for (int r = 0; r < 8; ++r)
                    #pragma unroll
                    for (int c = 0; c < 8; ++c)
                        acc[r][c] = fmaf(av[r], bv[c], acc[r][c]);
            }
        }
        #pragma unroll
        for (int c = 0; c < 8; ++c) {
            const int j = j0 + tx * 8 + c;
            const float dj = Dsf[tx * 8 + c];
            #pragma unroll
            for (int r = 0; r < 8; ++r) {
                const int ig = i0 + ty * 8 + r;
                float v = fmaf(-2.0f, acc[r][c], dj);
                v = (j == ig) ? FLT_MAX : v;
                const bool lt = v < m1[r];
                m2[r] = fminf(m2[r], fmaxf(m1[r], v));
                m1[r] = fminf(m1[r], v);
                i1[r] = lt ? j : i1[r];
            }
        }
    }
    __syncthreads();
    #pragma unroll
    for (int r = 0; r < 8; ++r) {
        float* s = &Scrf[((ty * 8 + r) * 32 + tx) * 3];
        s[0] = m1[r]; s[1] = __int_as_float(i1[r]); s[2] = m2[r];
    }
    __syncthreads();
    if (tid < FTI) {
        float M1 = FLT_MAX, M2 = FLT_MAX; int I1 = 0;
        for (int t = 0; t < 32; ++t) {
            const float* s = &Scrf[(tid * 32 + t) * 3];
            const float v1 = s[0]; const int ii = __float_as_int(s[1]);
            const float v2 = s[2];
            if (v1 < M1 || (v1 == M1 && ii < I1)) {
                M2 = fminf(M2, M1); M1 = v1; I1 = ii;
            } else {
                M2 = fminf(M2, v1);
            }
            M2 = fminf(M2, v2);
        }
        const int   gi = i0 + tid;
        const float di = db[gi];
        const float d1 = sqrtf(fmaxf(di + M1, 0.0f) + 1e-9f);
        const float d2 = sqrtf(fmaxf(di + M2, 0.0f) + 1e-9f);
        const float e  = expf(d1);
        const float pred = (d1 / d2 < 0.6f) ? 2.0f / (1.0f + e)
                                            : 2.0f / (1.0f + 2.0f * e);
        out[(size_t)batch * NN + gi] = pred;
        out[(size_t)NB * NN + (size_t)batch * NN + gi] = (float)I1;
    }
}

extern "C" void kernel_launch(void* const* d_in, const int* in_sizes, int n_in,
                              void* d_out, int out_size, void* d_ws, size_t ws_size,
                              hipStream_t stream) {
    const float* x = (const float*)d_in[0];
    float* out     = (float*)d_out;
    const size_t n_elem = (size_t)NB * NN * NC;
    const size_t need   = n_elem * 4 + (size_t)NB * NN * 4;   // interleaved hi/lo f16 + diag
    if (ws_size >= need) {
        f16*   xhl  = (f16*)d_ws;
        float* diag = (float*)(xhl + n_elem * 2);
        prep_kernel<<<dim3(NB * NN / 4), dim3(256), 0, stream>>>(x, xhl, diag);
        fcm_mfma<<<dim3(256), dim3(512), 0, stream>>>(xhl, diag, out);
    } else {
        float* diag = (float*)d_ws;
        diag_kernel<<<dim3(NB * NN / 4), dim3(256), 0, stream>>>(x, diag);
        fcm_fallback<<<dim3(256), dim3(256), 0, stream>>>(x, diag, out);
    }
}